// Round 4
// baseline (443.286 us; speedup 1.0000x reference)
//
#include <hip/hip_runtime.h>
#include <hip/hip_bf16.h>
#include <cstdint>
#include <cstddef>

#define C_IN 768
#define HW 120
#define WP 122
#define PIX (HW*HW)       // 14400
#define PPIX (WP*WP)      // 14884
#define S_CH 48

// ws layout (bytes)
#define OFF_POOL 0                    // 768*51*4 = 156672
#define OFF_HDD3 163840               // 48 floats
#define OFF_WT   262144               // 9*768*768*2 = 10616832
#define OFF_XTP  10878976             // 14884*768*2 = 22861824 ; end ~33.7MB

typedef __attribute__((ext_vector_type(8))) short short8;
typedef __attribute__((ext_vector_type(4))) float floatx4;
typedef __attribute__((ext_vector_type(4))) uint uint4v;

__device__ inline ushort f2bf(float f) {
  union { float f; uint i; } v; v.f = f;
  uint r = v.i + 0x7FFF + ((v.i >> 16) & 1);   // round-to-nearest-even
  return (ushort)(r >> 16);
}

// PyTorch bicubic(3->5), a=-0.75, align_corners=False, border-replicate
__device__ __constant__ float M35[5][3] = {
  { 1.096f, -0.096f,  0.000f },
  { 0.612f,  0.460f, -0.072f },
  { 0.000f,  1.000f,  0.000f },
  {-0.072f,  0.460f,  0.612f },
  { 0.000f, -0.096f,  1.096f },
};

// ---------------- K0: zero-pad + transpose x (C,H,W) f32 -> xTp (122*122, C) bf16 ----
__global__ __launch_bounds__(256) void k_pad_transpose(const float* __restrict__ x,
                                                       ushort* __restrict__ xTp) {
  int ph = blockIdx.x;   // padded row 0..121
  int tid = threadIdx.x;
  ushort* row = xTp + (size_t)ph * WP * C_IN;
  if (ph == 0 || ph == WP - 1) {
    uint4v z = {0, 0, 0, 0};
    for (int i = tid; i < WP * C_IN / 8; i += 256) ((uint4v*)row)[i] = z;
    return;
  }
  int h = ph - 1;
  for (int c = tid; c < C_IN; c += 256) {
    row[c] = 0;
    row[(size_t)(WP - 1) * C_IN + c] = 0;
  }
  for (int wc = 0; wc < 15; wc++) {
    for (int c = tid; c < C_IN; c += 256) {
      const float* s = x + (size_t)c * PIX + h * HW + wc * 8;
      floatx4 a = *(const floatx4*)s;
      floatx4 b = *(const floatx4*)(s + 4);
      ushort e[8];
#pragma unroll
      for (int j = 0; j < 4; j++) { e[j] = f2bf(a[j]); e[4 + j] = f2bf(b[j]); }
#pragma unroll
      for (int j = 0; j < 8; j++)
        row[(size_t)(1 + wc * 8 + j) * C_IN + c] = e[j];  // consecutive c per lane -> coalesced
    }
  }
}

// ---------------- K1: pooling per channel: a1, a3u (bicubic), a5 -> pooled[c][51] -----
__global__ __launch_bounds__(256) void k_pool(const float* __restrict__ x,
                                              float* __restrict__ pooled) {
  int c = blockIdx.x;
  int tid = threadIdx.x;
  __shared__ float fine[225];   // 15x15 grid of 8x8 block sums
  if (tid < 225) {
    int fr = tid / 15, fc = tid % 15;
    const float* base = x + (size_t)c * PIX + fr * 8 * HW + fc * 8;
    float s = 0.f;
#pragma unroll
    for (int r = 0; r < 8; r++) {
      floatx4 a = *(const floatx4*)(base + r * HW);
      floatx4 b = *(const floatx4*)(base + r * HW + 4);
#pragma unroll
      for (int j = 0; j < 4; j++) s += a[j] + b[j];
    }
    fine[tid] = s;
  }
  __syncthreads();
  if (tid == 0) {
    float a3[3][3], a5[5][5]; float tot = 0.f;
    for (int i = 0; i < 3; i++) for (int j = 0; j < 3; j++) {
      float s = 0.f;
      for (int a = 0; a < 5; a++) for (int b = 0; b < 5; b++) s += fine[(i*5+a)*15 + j*5+b];
      a3[i][j] = s / 1600.f; tot += s;
    }
    for (int i = 0; i < 5; i++) for (int j = 0; j < 5; j++) {
      float s = 0.f;
      for (int a = 0; a < 3; a++) for (int b = 0; b < 3; b++) s += fine[(i*3+a)*15 + j*3+b];
      a5[i][j] = s / 576.f;
    }
    float* out = pooled + c * 51;
    out[0] = tot / 14400.f;
    for (int p = 0; p < 5; p++) for (int q = 0; q < 5; q++) {
      float s = 0.f;
      for (int i = 0; i < 3; i++) for (int j = 0; j < 3; j++)
        s += M35[p][i] * M35[q][j] * a3[i][j];
      out[1 + p*5 + q] = s;       // a3u
      out[26 + p*5 + q] = a5[p][q];
    }
  }
}

// ---------------- K2: routing MLP -> hdd3[48] ----------------------------------------
__global__ __launch_bounds__(256) void k_route(const float* __restrict__ pooled,
                                               const float* __restrict__ w_pw1,
                                               const float* __restrict__ w_dw1,
                                               const float* __restrict__ w_dw2,
                                               float* __restrict__ hdd3) {
  int s = blockIdx.x;  // 0..47
  int tid = threadIdx.x;
  __shared__ float red[26][256];
  float acc[25]; float accw1 = 0.f;
#pragma unroll
  for (int q = 0; q < 25; q++) acc[q] = 0.f;
  for (int c = tid; c < C_IN; c += 256) {
    const float* pl = pooled + c * 51;
    float w1 = w_pw1[(size_t)s * 3 * C_IN + c];
    float w2 = w_pw1[(size_t)s * 3 * C_IN + C_IN + c];
    float w3 = w_pw1[(size_t)s * 3 * C_IN + 2 * C_IN + c];
    accw1 += w1 * pl[0];
#pragma unroll
    for (int q = 0; q < 25; q++) acc[q] += w2 * pl[1 + q] + w3 * pl[26 + q];
  }
#pragma unroll
  for (int q = 0; q < 25; q++) red[q][tid] = acc[q];
  red[25][tid] = accw1;
  for (int st = 128; st; st >>= 1) {
    __syncthreads();
    if (tid < st)
      for (int q = 0; q < 26; q++) red[q][tid] += red[q][tid + st];
  }
  __syncthreads();
  if (tid == 0) {
    float hdd[5][5];
    for (int p = 0; p < 5; p++) for (int q = 0; q < 5; q++) {
      float v = red[p*5+q][0] + red[25][0];
      hdd[p][q] = v > 0.f ? v : 0.f;
    }
    float wd1[9], wd2[9];
    for (int i = 0; i < 9; i++) { wd1[i] = w_dw1[s*9 + i]; wd2[i] = w_dw2[s*9 + i]; }
    float h2[3][3];
    for (int i = 0; i < 3; i++) for (int j = 0; j < 3; j++) {
      float v = 0.f;
      for (int u = 0; u < 3; u++) for (int vv = 0; vv < 3; vv++) v += wd1[u*3+vv] * hdd[i+u][j+vv];
      h2[i][j] = v > 0.f ? v : 0.f;
    }
    float v = 0.f;
    for (int u = 0; u < 3; u++) for (int vv = 0; vv < 3; vv++) v += wd2[u*3+vv] * h2[u][vv];
    hdd3[s] = v > 0.f ? v : 0.f;
  }
}

// ---------------- K3: gates + weight synthesis -> wt[tap][o][c] (bf16) ---------------
__global__ __launch_bounds__(256) void k_wt(const float* __restrict__ convs,
                                            const float* __restrict__ w_pw2,
                                            const float* __restrict__ hdd3,
                                            ushort* __restrict__ wt) {
  int o = blockIdx.x;  // 0..767
  int tid = threadIdx.x;
  __shared__ float g[3];
  if (tid < 3) {
    float v = 0.f;
    for (int s = 0; s < S_CH; s++)
      v += w_pw2[((size_t)tid * C_IN + o) * S_CH + s] * hdd3[s];
    g[tid] = 1.f / (1.f + __expf(-v));
  }
  __syncthreads();
  float g0 = g[0], g1 = g[1], g2 = g[2];
  const float* c0p = convs + (size_t)o * 6912;
  const float* c1p = convs + (size_t)(C_IN + o) * 6912;
  const float* c2p = convs + (size_t)(2 * C_IN + o) * 6912;
  for (int c = tid; c < C_IN; c += 256) {
#pragma unroll
    for (int tap = 0; tap < 9; tap++) {
      float v = g0 * c0p[c*9 + tap] + g1 * c1p[c*9 + tap] + g2 * c2p[c*9 + tap];
      wt[((size_t)tap * C_IN + o) * C_IN + c] = f2bf(v);
    }
  }
}

// ---------------- K4: main conv as 9 shifted GEMMs, MFMA 16x16x32 bf16 ---------------
// Block: 128 M (8 rows x 16 cols of output) x 128 N, 4 waves in 2x2, BK=32.
// Staging: register path (global_load_dwordx4 -> ds_write_b128). OUTPUT: f32.
__global__ __launch_bounds__(256) void k_conv(const ushort* __restrict__ xTp,
                                              const ushort* __restrict__ wt,
                                              float* __restrict__ y) {
  __shared__ __align__(16) ushort Atile[128 * 32];
  __shared__ __align__(16) ushort Btile[128 * 32];
  int tid = threadIdx.x;
  int lane = tid & 63;
  int quad = lane >> 4, l15 = lane & 15;
  int wave = tid >> 6;
  int wave_m = wave >> 1, wave_n = wave & 1;
  int n0 = blockIdx.x * 128;
  int w0 = blockIdx.y * 16;
  int h0 = blockIdx.z * 8;

  floatx4 acc[4][4];
#pragma unroll
  for (int i = 0; i < 4; i++)
#pragma unroll
    for (int j = 0; j < 4; j++) acc[i][j] = (floatx4){0.f, 0.f, 0.f, 0.f};

  int cid0 = tid, cid1 = 256 + tid;
  int am0 = cid0 >> 2, as0 = cid0 & 3;
  int am1 = cid1 >> 2, as1 = cid1 & 3;
  int ar0 = am0 >> 4, ac0 = am0 & 15;
  int ar1 = am1 >> 4, ac1 = am1 & 15;

  for (int tap = 0; tap < 9; tap++) {
    int kh = tap / 3, kw = tap % 3;
    int pA0 = (h0 + ar0 + kh) * WP + (w0 + ac0 + kw);
    int pA1 = (h0 + ar1 + kh) * WP + (w0 + ac1 + kw);
    pA0 = min(pA0, PPIX - 1);   // clamp: only affects discarded (w>=120) outputs
    pA1 = min(pA1, PPIX - 1);
    const ushort* baseA0 = xTp + (size_t)pA0 * C_IN + as0 * 8;
    const ushort* baseA1 = xTp + (size_t)pA1 * C_IN + as1 * 8;
    const ushort* baseB0 = wt + ((size_t)(tap * C_IN + n0 + am0)) * C_IN + as0 * 8;
    const ushort* baseB1 = wt + ((size_t)(tap * C_IN + n0 + am1)) * C_IN + as1 * 8;

    for (int cc = 0; cc < 24; cc++) {
      int c0 = cc * 32;
      uint4v va0 = *(const uint4v*)(baseA0 + c0);
      uint4v va1 = *(const uint4v*)(baseA1 + c0);
      uint4v vb0 = *(const uint4v*)(baseB0 + c0);
      uint4v vb1 = *(const uint4v*)(baseB1 + c0);
      *(uint4v*)&Atile[cid0 * 8] = va0;
      *(uint4v*)&Atile[cid1 * 8] = va1;
      *(uint4v*)&Btile[cid0 * 8] = vb0;
      *(uint4v*)&Btile[cid1 * 8] = vb1;
      __syncthreads();

      short8 af[4], bfr[4];
#pragma unroll
      for (int mt = 0; mt < 4; mt++) {
        int m = wave_m * 64 + mt * 16 + l15;
        af[mt] = *(const short8*)&Atile[m * 32 + quad * 8];
      }
#pragma unroll
      for (int nt = 0; nt < 4; nt++) {
        int n = wave_n * 64 + nt * 16 + l15;
        bfr[nt] = *(const short8*)&Btile[n * 32 + quad * 8];
      }
#pragma unroll
      for (int mt = 0; mt < 4; mt++)
#pragma unroll
        for (int nt = 0; nt < 4; nt++)
          acc[mt][nt] = __builtin_amdgcn_mfma_f32_16x16x32_bf16(af[mt], bfr[nt], acc[mt][nt], 0, 0, 0);

      __syncthreads();
    }
  }

  // epilogue: D layout col(n)=lane&15, row(m)=quad*4+reg
  // tile row m = wave_m*64 + mt*16 + (quad*4+reg) -> h = h0+wave_m*4+mt, w = w0+quad*4+reg
  // OUTPUT IS FLOAT32: 4 acc regs = 4 consecutive w -> one float4 store
#pragma unroll
  for (int mt = 0; mt < 4; mt++) {
    int h = h0 + wave_m * 4 + mt;
    int wbase = w0 + quad * 4;
    if (wbase < HW) {
#pragma unroll
      for (int nt = 0; nt < 4; nt++) {
        int n = n0 + wave_n * 64 + nt * 16 + l15;
        *(floatx4*)&y[(size_t)n * PIX + h * HW + wbase] = acc[mt][nt];
      }
    }
  }
}

extern "C" void kernel_launch(void* const* d_in, const int* in_sizes, int n_in,
                              void* d_out, int out_size, void* d_ws, size_t ws_size,
                              hipStream_t stream) {
  const float* x     = (const float*)d_in[0];
  const float* convs = (const float*)d_in[1];
  const float* w_pw1 = (const float*)d_in[2];
  const float* w_dw1 = (const float*)d_in[3];
  const float* w_dw2 = (const float*)d_in[4];
  const float* w_pw2 = (const float*)d_in[5];
  float* y = (float*)d_out;
  char* ws = (char*)d_ws;
  float*  pooled = (float*)(ws + OFF_POOL);
  float*  hdd3   = (float*)(ws + OFF_HDD3);
  ushort* wt     = (ushort*)(ws + OFF_WT);
  ushort* xTp    = (ushort*)(ws + OFF_XTP);

  hipLaunchKernelGGL(k_pad_transpose, dim3(122), dim3(256), 0, stream, x, xTp);
  hipLaunchKernelGGL(k_pool,          dim3(768), dim3(256), 0, stream, x, pooled);
  hipLaunchKernelGGL(k_route,         dim3(48),  dim3(256), 0, stream, pooled, w_pw1, w_dw1, w_dw2, hdd3);
  hipLaunchKernelGGL(k_wt,            dim3(768), dim3(256), 0, stream, convs, w_pw2, hdd3, wt);
  hipLaunchKernelGGL(k_conv,          dim3(6, 8, 15), dim3(256), 0, stream, xTp, wt, y);
}

// Round 6
// 440.424 us; speedup vs baseline: 1.0065x; 1.0065x over previous
//
#include <hip/hip_runtime.h>
#include <hip/hip_bf16.h>
#include <cstdint>
#include <cstddef>

#define C_IN 768
#define HW 120
#define WP 122
#define PIX (HW*HW)       // 14400
#define PPIX (WP*WP)      // 14884
#define S_CH 48
#define CCH 256           // channel chunk for transpose
#define LSTR 257          // LDS row stride (ushorts), 257 % 32 == 1 -> conflict-free

// ws layout (bytes)
#define OFF_POOL 0                    // 768*51*4 = 156672
#define OFF_HDD3 163840               // 48 floats
#define OFF_WT   262144               // 9*768*768*2 = 10616832
#define OFF_XTP  10878976             // 14884*768*2 = 22861824 ; end ~33.7MB

typedef __attribute__((ext_vector_type(8))) short short8;
typedef __attribute__((ext_vector_type(4))) float floatx4;
typedef __attribute__((ext_vector_type(4))) uint uint4v;

#define AS3(p) ((__attribute__((address_space(3))) uint*)(p))
#define AS1(p) ((const __attribute__((address_space(1))) uint*)(p))

__device__ inline ushort f2bf(float f) {
  union { float f; uint i; } v; v.f = f;
  uint r = v.i + 0x7FFF + ((v.i >> 16) & 1);   // round-to-nearest-even
  return (ushort)(r >> 16);
}

// PyTorch bicubic(3->5), a=-0.75, align_corners=False, border-replicate
__device__ __constant__ float M35[5][3] = {
  { 1.096f, -0.096f,  0.000f },
  { 0.612f,  0.460f, -0.072f },
  { 0.000f,  1.000f,  0.000f },
  {-0.072f,  0.460f,  0.612f },
  { 0.000f, -0.096f,  1.096f },
};

// ---------------- K0: zero-pad + transpose x (C,H,W) f32 -> xTp (122*122, C) bf16 ----
// Coalesced LDS-transpose version. grid (122 rows, 3 c-chunks), 256 thr.
__global__ __launch_bounds__(256) void k_pad_transpose(const float* __restrict__ x,
                                                       ushort* __restrict__ xTp) {
  int ph = blockIdx.x;          // padded row 0..121
  int c0 = blockIdx.y * CCH;    // 0, 256, 512
  int tid = threadIdx.x;
  ushort* rowbase = xTp + (size_t)ph * WP * C_IN;
  if (ph == 0 || ph == WP - 1) {
    uint4v z = {0, 0, 0, 0};
    for (int i = tid; i < WP * (CCH / 8); i += 256) {
      int w = i / (CCH / 8), j = i % (CCH / 8);
      *(uint4v*)&rowbase[(size_t)w * C_IN + c0 + j * 8] = z;
    }
    return;
  }
  int h = ph - 1;
  __shared__ ushort T[HW * LSTR];   // 120*257*2 = 61680 B
  int wave = tid >> 6, lane = tid & 63;
  // phase 1: wave reads 64 channels' rows, coalesced float2 (480 B/row)
  for (int k = 0; k < 64; k++) {
    int cl = wave * 64 + k;                       // local channel 0..255
    const float* src = x + (size_t)(c0 + cl) * PIX + h * HW;
    if (lane < 60) {
      float vx = src[2 * lane], vy = src[2 * lane + 1];
      T[(2 * lane) * LSTR + cl]     = f2bf(vx);
      T[(2 * lane + 1) * LSTR + cl] = f2bf(vy);
    }
  }
  __syncthreads();
  // phase 2: coalesced packed-uint writes, + zero pad columns w=0, w=121
  if (tid < 128) {
    *(uint*)&rowbase[c0 + 2 * tid] = 0;
    *(uint*)&rowbase[(size_t)(WP - 1) * C_IN + c0 + 2 * tid] = 0;
  }
  for (int idx = tid; idx < HW * (CCH / 2); idx += 256) {
    int w = idx >> 7, pr = idx & 127;
    uint a = T[w * LSTR + 2 * pr];
    uint b = T[w * LSTR + 2 * pr + 1];
    *(uint*)&rowbase[(size_t)(1 + w) * C_IN + c0 + 2 * pr] = a | (b << 16);
  }
}

// ---------------- K1: pooling per channel: a1, a3u (bicubic), a5 -> pooled[c][51] -----
__global__ __launch_bounds__(256) void k_pool(const float* __restrict__ x,
                                              float* __restrict__ pooled) {
  int c = blockIdx.x;
  int tid = threadIdx.x;
  __shared__ float fine[225];   // 15x15 grid of 8x8 block sums
  if (tid < 225) {
    int fr = tid / 15, fc = tid % 15;
    const float* base = x + (size_t)c * PIX + fr * 8 * HW + fc * 8;
    float s = 0.f;
#pragma unroll
    for (int r = 0; r < 8; r++) {
      floatx4 a = *(const floatx4*)(base + r * HW);
      floatx4 b = *(const floatx4*)(base + r * HW + 4);
#pragma unroll
      for (int j = 0; j < 4; j++) s += a[j] + b[j];
    }
    fine[tid] = s;
  }
  __syncthreads();
  if (tid == 0) {
    float a3[3][3], a5[5][5]; float tot = 0.f;
    for (int i = 0; i < 3; i++) for (int j = 0; j < 3; j++) {
      float s = 0.f;
      for (int a = 0; a < 5; a++) for (int b = 0; b < 5; b++) s += fine[(i*5+a)*15 + j*5+b];
      a3[i][j] = s / 1600.f; tot += s;
    }
    for (int i = 0; i < 5; i++) for (int j = 0; j < 5; j++) {
      float s = 0.f;
      for (int a = 0; a < 3; a++) for (int b = 0; b < 3; b++) s += fine[(i*3+a)*15 + j*3+b];
      a5[i][j] = s / 576.f;
    }
    float* out = pooled + c * 51;
    out[0] = tot / 14400.f;
    for (int p = 0; p < 5; p++) for (int q = 0; q < 5; q++) {
      float s = 0.f;
      for (int i = 0; i < 3; i++) for (int j = 0; j < 3; j++)
        s += M35[p][i] * M35[q][j] * a3[i][j];
      out[1 + p*5 + q] = s;       // a3u
      out[26 + p*5 + q] = a5[p][q];
    }
  }
}

// ---------------- K2: routing MLP -> hdd3[48] ----------------------------------------
__global__ __launch_bounds__(256) void k_route(const float* __restrict__ pooled,
                                               const float* __restrict__ w_pw1,
                                               const float* __restrict__ w_dw1,
                                               const float* __restrict__ w_dw2,
                                               float* __restrict__ hdd3) {
  int s = blockIdx.x;  // 0..47
  int tid = threadIdx.x;
  __shared__ float red[26][256];
  float acc[25]; float accw1 = 0.f;
#pragma unroll
  for (int q = 0; q < 25; q++) acc[q] = 0.f;
  for (int c = tid; c < C_IN; c += 256) {
    const float* pl = pooled + c * 51;
    float w1 = w_pw1[(size_t)s * 3 * C_IN + c];
    float w2 = w_pw1[(size_t)s * 3 * C_IN + C_IN + c];
    float w3 = w_pw1[(size_t)s * 3 * C_IN + 2 * C_IN + c];
    accw1 += w1 * pl[0];
#pragma unroll
    for (int q = 0; q < 25; q++) acc[q] += w2 * pl[1 + q] + w3 * pl[26 + q];
  }
#pragma unroll
  for (int q = 0; q < 25; q++) red[q][tid] = acc[q];
  red[25][tid] = accw1;
  for (int st = 128; st; st >>= 1) {
    __syncthreads();
    if (tid < st)
      for (int q = 0; q < 26; q++) red[q][tid] += red[q][tid + st];
  }
  __syncthreads();
  if (tid == 0) {
    float hdd[5][5];
    for (int p = 0; p < 5; p++) for (int q = 0; q < 5; q++) {
      float v = red[p*5+q][0] + red[25][0];
      hdd[p][q] = v > 0.f ? v : 0.f;
    }
    float wd1[9], wd2[9];
    for (int i = 0; i < 9; i++) { wd1[i] = w_dw1[s*9 + i]; wd2[i] = w_dw2[s*9 + i]; }
    float h2[3][3];
    for (int i = 0; i < 3; i++) for (int j = 0; j < 3; j++) {
      float v = 0.f;
      for (int u = 0; u < 3; u++) for (int vv = 0; vv < 3; vv++) v += wd1[u*3+vv] * hdd[i+u][j+vv];
      h2[i][j] = v > 0.f ? v : 0.f;
    }
    float v = 0.f;
    for (int u = 0; u < 3; u++) for (int vv = 0; vv < 3; vv++) v += wd2[u*3+vv] * h2[u][vv];
    hdd3[s] = v > 0.f ? v : 0.f;
  }
}

// ---------------- K3: gates + weight synthesis -> wt[tap][o][c] (bf16) ---------------
__global__ __launch_bounds__(256) void k_wt(const float* __restrict__ convs,
                                            const float* __restrict__ w_pw2,
                                            const float* __restrict__ hdd3,
                                            ushort* __restrict__ wt) {
  int o = blockIdx.x;  // 0..767
  int tid = threadIdx.x;
  __shared__ float g[3];
  if (tid < 3) {
    float v = 0.f;
    for (int s = 0; s < S_CH; s++)
      v += w_pw2[((size_t)tid * C_IN + o) * S_CH + s] * hdd3[s];
    g[tid] = 1.f / (1.f + __expf(-v));
  }
  __syncthreads();
  float g0 = g[0], g1 = g[1], g2 = g[2];
  const float* c0p = convs + (size_t)o * 6912;
  const float* c1p = convs + (size_t)(C_IN + o) * 6912;
  const float* c2p = convs + (size_t)(2 * C_IN + o) * 6912;
  for (int c = tid; c < C_IN; c += 256) {
#pragma unroll
    for (int tap = 0; tap < 9; tap++) {
      float v = g0 * c0p[c*9 + tap] + g1 * c1p[c*9 + tap] + g2 * c2p[c*9 + tap];
      wt[((size_t)tap * C_IN + o) * C_IN + c] = f2bf(v);
    }
  }
}

// ---------------- K4: main conv as 9 shifted GEMMs, MFMA 16x16x32 bf16 ---------------
// Block: 128 M (8 rows x 16 cols of output) x 128 N, 4 waves in 2x2, BK=32.
// Staging: global_load_lds width=16 (m97 pattern). OUTPUT: f32.
__global__ __launch_bounds__(256) void k_conv(const ushort* __restrict__ xTp,
                                              const ushort* __restrict__ wt,
                                              float* __restrict__ y) {
  __shared__ __align__(16) ushort Atile[128 * 32];
  __shared__ __align__(16) ushort Btile[128 * 32];
  int tid = threadIdx.x;
  int lane = tid & 63;
  int quad = lane >> 4, l15 = lane & 15;
  int wave = tid >> 6;
  int wave_m = wave >> 1, wave_n = wave & 1;
  int n0 = blockIdx.x * 128;
  int w0 = blockIdx.y * 16;
  int h0 = blockIdx.z * 8;

  floatx4 acc[4][4];
#pragma unroll
  for (int i = 0; i < 4; i++)
#pragma unroll
    for (int j = 0; j < 4; j++) acc[i][j] = (floatx4){0.f, 0.f, 0.f, 0.f};

  // chunk ids this thread stages: cid = wave*128 + i*64 + lane, i in {0,1}
  int cid0 = wave * 128 + lane, cid1 = wave * 128 + 64 + lane;
  int am0 = cid0 >> 2, as0 = cid0 & 3;
  int am1 = cid1 >> 2, as1 = cid1 & 3;
  int ar0 = am0 >> 4, ac0 = am0 & 15;
  int ar1 = am1 >> 4, ac1 = am1 & 15;
  // wave-uniform LDS bases (HW scatters lane j at base + 16*j)
  auto ldsA0 = AS3(&Atile[(size_t)(wave * 128) * 8]);
  auto ldsA1 = AS3(&Atile[(size_t)(wave * 128 + 64) * 8]);
  auto ldsB0 = AS3(&Btile[(size_t)(wave * 128) * 8]);
  auto ldsB1 = AS3(&Btile[(size_t)(wave * 128 + 64) * 8]);

  for (int tap = 0; tap < 9; tap++) {
    int kh = tap / 3, kw = tap % 3;
    int pA0 = (h0 + ar0 + kh) * WP + (w0 + ac0 + kw);
    int pA1 = (h0 + ar1 + kh) * WP + (w0 + ac1 + kw);
    pA0 = min(pA0, PPIX - 1);   // clamp: only affects discarded (w>=120) outputs
    pA1 = min(pA1, PPIX - 1);
    const ushort* baseA0 = xTp + (size_t)pA0 * C_IN + as0 * 8;
    const ushort* baseA1 = xTp + (size_t)pA1 * C_IN + as1 * 8;
    const ushort* baseB0 = wt + ((size_t)(tap * C_IN + n0 + am0)) * C_IN + as0 * 8;
    const ushort* baseB1 = wt + ((size_t)(tap * C_IN + n0 + am1)) * C_IN + as1 * 8;

    for (int cc = 0; cc < 24; cc++) {
      int c0 = cc * 32;
      __builtin_amdgcn_global_load_lds(AS1(baseA0 + c0), ldsA0, 16, 0, 0);
      __builtin_amdgcn_global_load_lds(AS1(baseA1 + c0), ldsA1, 16, 0, 0);
      __builtin_amdgcn_global_load_lds(AS1(baseB0 + c0), ldsB0, 16, 0, 0);
      __builtin_amdgcn_global_load_lds(AS1(baseB1 + c0), ldsB1, 16, 0, 0);
      __syncthreads();

      short8 af[4], bfr[4];
#pragma unroll
      for (int mt = 0; mt < 4; mt++) {
        int m = wave_m * 64 + mt * 16 + l15;
        af[mt] = *(const short8*)&Atile[m * 32 + quad * 8];
      }
#pragma unroll
      for (int nt = 0; nt < 4; nt++) {
        int n = wave_n * 64 + nt * 16 + l15;
        bfr[nt] = *(const short8*)&Btile[n * 32 + quad * 8];
      }
#pragma unroll
      for (int mt = 0; mt < 4; mt++)
#pragma unroll
        for (int nt = 0; nt < 4; nt++)
          acc[mt][nt] = __builtin_amdgcn_mfma_f32_16x16x32_bf16(af[mt], bfr[nt], acc[mt][nt], 0, 0, 0);

      __syncthreads();
    }
  }

  // epilogue: D layout col(n)=lane&15, row(m)=quad*4+reg
  // tile row m = wave_m*64 + mt*16 + (quad*4+reg) -> h = h0+wave_m*4+mt, w = w0+quad*4+reg
  // OUTPUT IS FLOAT32: 4 acc regs = 4 consecutive w -> one float4 store
#pragma unroll
  for (int mt = 0; mt < 4; mt++) {
    int h = h0 + wave_m * 4 + mt;
    int wbase = w0 + quad * 4;
    if (wbase < HW) {
#pragma unroll
      for (int nt = 0; nt < 4; nt++) {
        int n = n0 + wave_n * 64 + nt * 16 + l15;
        *(floatx4*)&y[(size_t)n * PIX + h * HW + wbase] = acc[mt][nt];
      }
    }
  }
}

extern "C" void kernel_launch(void* const* d_in, const int* in_sizes, int n_in,
                              void* d_out, int out_size, void* d_ws, size_t ws_size,
                              hipStream_t stream) {
  const float* x     = (const float*)d_in[0];
  const float* convs = (const float*)d_in[1];
  const float* w_pw1 = (const float*)d_in[2];
  const float* w_dw1 = (const float*)d_in[3];
  const float* w_dw2 = (const float*)d_in[4];
  const float* w_pw2 = (const float*)d_in[5];
  float* y = (float*)d_out;
  char* ws = (char*)d_ws;
  float*  pooled = (float*)(ws + OFF_POOL);
  float*  hdd3   = (float*)(ws + OFF_HDD3);
  ushort* wt     = (ushort*)(ws + OFF_WT);
  ushort* xTp    = (ushort*)(ws + OFF_XTP);

  hipLaunchKernelGGL(k_pad_transpose, dim3(122, 3), dim3(256), 0, stream, x, xTp);
  hipLaunchKernelGGL(k_pool,          dim3(768),    dim3(256), 0, stream, x, pooled);
  hipLaunchKernelGGL(k_route,         dim3(48),     dim3(256), 0, stream, pooled, w_pw1, w_dw1, w_dw2, hdd3);
  hipLaunchKernelGGL(k_wt,            dim3(768),    dim3(256), 0, stream, convs, w_pw2, hdd3, wt);
  hipLaunchKernelGGL(k_conv,          dim3(6, 8, 15), dim3(256), 0, stream, xTp, wt, y);
}